// Round 7
// baseline (66.582 us; speedup 1.0000x reference)
//
#include <hip/hip_runtime.h>

// WOMD post-processing v7: ONE agent per 64-lane wave (4096 waves = 4/SIMD,
// 2x the TLP of v2) to hide DS-chain + scattered-load latency. Lanes 32-63
// mirror the selection math (VALU is not the constraint); gather/store uses
// all 64 lanes (96 F3 -> 1.5/lane). All FP op orders identical to v2.

#define NSC 64
#define NAG 64
#define NJF 32
#define NSTEP 80
#define KP 6
#define TOUT 16

struct F3 { float x, y, z; };

__global__ __launch_bounds__(64)
void womd_pp7(const float* __restrict__ ag_type,
              const float* __restrict__ trajs,
              const float* __restrict__ scores,
              float* __restrict__ out)
{
    const int tid = threadIdx.x;
    const int hl  = tid & 31;           // mode index (lanes 32-63 mirror)
    const int b   = blockIdx.x;         // 0..4095
    const int s   = b >> 6;             // scene
    const int a   = b & 63;             // agent

    __shared__ float exs[NJF][2];       // endpoints
    __shared__ float sms[NJF];          // softmax scores
    __shared__ int   selsh[KP];         // MTR picks

    // ---- loads (issued up front) ----
    float raw = scores[((size_t)s * NJF + hl) * NAG + a];
    size_t eoff = (((size_t)(s * NJF + hl) * NAG + a) * NSTEP + (NSTEP - 1)) * 3;
    float exx = trajs[eoff];
    float exy = trajs[eoff + 1];
    const float* at = ag_type + (size_t)(s * NAG + a) * 3;
    const float thresh = at[0] * 2.5f + at[1] * 1.0f + at[2] * 2.0f;

    if (tid < NJF) {
        exs[hl][0] = exx;
        exs[hl][1] = exy;
    }

    // ---- softmax over 32 modes (width-32 butterfly, 1 expf/lane) ----
    float mx = raw;
    #pragma unroll
    for (int off = 16; off > 0; off >>= 1)
        mx = fmaxf(mx, __shfl_xor(mx, off, 32));
    float ev = expf(raw - mx);
    float sum = ev;
    #pragma unroll
    for (int off = 16; off > 0; off >>= 1)
        sum += __shfl_xor(sum, off, 32);
    float sm = ev / sum;
    if (tid < NJF) sms[hl] = sm;

    __syncthreads();

    // ---- within bitmask: row hl (strict <, sqrt like jnp.linalg.norm) ----
    unsigned m = 0;
    #pragma unroll 8
    for (int j = 0; j < NJF; ++j) {
        float dx = exx - exs[j][0];
        float dy = exy - exs[j][1];
        if (sqrtf(dx * dx + dy * dy) < thresh) m |= (1u << j);
    }

    // ---- MTR NMS: 6 picks, wave-parallel (identical to v2) ----
    float ls = sm;
    #pragma unroll
    for (int k = 0; k < KP; ++k) {
        float v = ls; int idx = hl;
        #pragma unroll
        for (int off = 16; off > 0; off >>= 1) {
            float ov = __shfl_xor(v, off, 32);
            int   oi = __shfl_xor(idx, off, 32);
            if (ov > v || (ov == v && oi < idx)) { v = ov; idx = oi; }
        }
        unsigned wb = __shfl(m, idx, 32);          // within-row of the pick
        ls *= ((wb >> hl) & 1u) ? 0.01f : 1.0f;
        if (hl == idx) ls = -1.0f;
        if (tid == 0) selsh[k] = idx;
    }
    __syncthreads();

    // ---- trajectory gather: 96 F3 over 64 lanes (issue before the tail) ----
    F3 pt0, pt1;
    {
        int mm = tid >> 4;              // 0..3
        int t  = tid & 15;
        int sj = selsh[mm];
        size_t src = (((size_t)(s * NJF + sj) * NAG + a) * NSTEP + (4 + 5 * t)) * 3;
        pt0 = *(const F3*)(trajs + src);
    }
    if (tid < 32) {
        int e  = 64 + tid;              // 64..95
        int mm = e >> 4;                // 4..5
        int t  = e & 15;
        int sj = selsh[mm];
        size_t src = (((size_t)(s * NJF + sj) * NAG + a) * NSTEP + (4 + 5 * t)) * 3;
        pt1 = *(const F3*)(trajs + src);
    }

    // ---- MPA tail: serial 6x6 on lane 0 (identical math to v2) ----
    if (tid == 0) {
        int   sel[KP];
        float sk[KP], sx[KP], sy[KP];
        float ssum = 0.f;
        #pragma unroll
        for (int k = 0; k < KP; ++k) {
            sel[k] = selsh[k];
            sk[k]  = sms[sel[k]];
            ssum  += sk[k];
            sx[k]  = exs[sel[k]][0];
            sy[k]  = exs[sel[k]][1];
        }
        #pragma unroll
        for (int k = 0; k < KP; ++k) sk[k] /= ssum;

        bool w2[KP][KP];
        #pragma unroll
        for (int i = 0; i < KP; ++i)
            #pragma unroll
            for (int j = 0; j < KP; ++j) {
                float dx = sx[i] - sx[j], dy = sy[i] - sy[j];
                w2[i][j] = sqrtf(dx * dx + dy * dy) < thresh;
            }

        int order[KP]; bool used[KP] = {false,false,false,false,false,false};
        #pragma unroll
        for (int t = 0; t < KP; ++t) {
            int best = -1; float bv = 0.f;
            #pragma unroll
            for (int j = 0; j < KP; ++j)
                if (!used[j] && (best < 0 || sk[j] > bv)) { best = j; bv = sk[j]; }
            order[t] = best; used[best] = true;
        }
        #pragma unroll
        for (int t = 0; t < KP; ++t) {
            int k = order[t];
            bool any = false;
            #pragma unroll
            for (int j = 0; j < KP; ++j)
                if (w2[k][j] && sk[j] > sk[k]) any = true;
            if (any) sk[k] = 0.001f;
        }

        float s2 = 0.f;
        #pragma unroll
        for (int k = 0; k < KP; ++k) s2 += sk[k];
        #pragma unroll
        for (int k = 0; k < KP; ++k) sk[k] /= s2;
        float s3 = 0.f; float q[KP];
        #pragma unroll
        for (int k = 0; k < KP; ++k) { q[k] = sk[k] * sk[k]; s3 += q[k]; }

        const size_t SCBASE = (size_t)NSC * NAG * KP * TOUT * 3;
        size_t scb = SCBASE + ((size_t)s * NAG + a) * KP;
        #pragma unroll
        for (int k = 0; k < KP; ++k) out[scb + k] = q[k] / s3;
    }

    // ---- trajectory stores (loads were in flight during the tail) ----
    size_t ob = ((size_t)s * NAG + a) * (KP * TOUT * 3);
    *(F3*)(out + ob + (size_t)tid * 3) = pt0;
    if (tid < 32)
        *(F3*)(out + ob + (size_t)(64 + tid) * 3) = pt1;
}

extern "C" void kernel_launch(void* const* d_in, const int* in_sizes, int n_in,
                              void* d_out, int out_size, void* d_ws, size_t ws_size,
                              hipStream_t stream) {
    const float* ag_type = (const float*)d_in[0];
    const float* trajs   = (const float*)d_in[1];
    const float* scores  = (const float*)d_in[2];
    float* out = (float*)d_out;

    womd_pp7<<<NSC * NAG, 64, 0, stream>>>(ag_type, trajs, scores, out);
}

// Round 8
// 32.690 us; speedup vs baseline: 2.0368x; 2.0368x over previous
//
#include <hip/hip_runtime.h>

// WOMD post-processing v8: v2's per-wave structure VERBATIM, packed 4 waves
// per 256-thread workgroup (8 agents/WG) -> 512 WGs instead of 2048.
// Duration has tracked WG count (~16 ns/WG) across v0/v2/v5/v7; this tests
// (and exploits) the per-WG fixed cost. Each wave uses a private LDS slice,
// so no __syncthreads is needed (within-wave LDS ordering via lgkmcnt).

#define NSC 64
#define NAG 64
#define NJF 32
#define NSTEP 80
#define KP 6
#define TOUT 16

struct F3 { float x, y, z; };

__global__ __launch_bounds__(256)
void womd_pp8(const float* __restrict__ ag_type,
              const float* __restrict__ trajs,
              const float* __restrict__ scores,
              float* __restrict__ out)
{
    const int tid  = threadIdx.x;       // 0..255
    const int wid  = tid >> 6;          // wave 0..3
    const int half = (tid >> 5) & 1;    // agent of the wave's pair
    const int hl   = tid & 31;          // mode index within 32-group

    const int pg = blockIdx.x * 4 + wid;   // global pair index 0..2047
    const int s  = pg >> 5;                // scene
    const int p  = pg & 31;                // agent-pair within scene
    const int a  = p * 2 + half;           // agent

    __shared__ float exs[4][2][NJF][2];    // per-wave private slices
    __shared__ float sms[4][2][NJF];
    __shared__ int   selsh[4][2][KP];

    // ---- loads (issued up front) ----
    float raw = scores[((size_t)s * NJF + hl) * NAG + a];
    size_t eoff = (((size_t)(s * NJF + hl) * NAG + a) * NSTEP + (NSTEP - 1)) * 3;
    float exx = trajs[eoff];
    float exy = trajs[eoff + 1];
    const float* at = ag_type + (size_t)(s * NAG + a) * 3;
    const float thresh = at[0] * 2.5f + at[1] * 1.0f + at[2] * 2.0f;

    exs[wid][half][hl][0] = exx;
    exs[wid][half][hl][1] = exy;

    // ---- softmax over 32 modes (width-32 butterfly, 1 expf/lane) ----
    float mx = raw;
    #pragma unroll
    for (int off = 16; off > 0; off >>= 1)
        mx = fmaxf(mx, __shfl_xor(mx, off, 32));
    float ev = expf(raw - mx);
    float sum = ev;
    #pragma unroll
    for (int off = 16; off > 0; off >>= 1)
        sum += __shfl_xor(sum, off, 32);
    float sm = ev / sum;
    sms[wid][half][hl] = sm;

    // (no barrier: LDS slice is wave-private; lgkmcnt orders write->read)

    // ---- within bitmask: row hl (strict <, sqrt like jnp.linalg.norm) ----
    unsigned m = 0;
    #pragma unroll 8
    for (int j = 0; j < NJF; ++j) {
        float dx = exx - exs[wid][half][j][0];
        float dy = exy - exs[wid][half][j][1];
        if (sqrtf(dx * dx + dy * dy) < thresh) m |= (1u << j);
    }

    // ---- MTR NMS: 6 picks, wave-parallel (identical to v2) ----
    float ls = sm;
    #pragma unroll
    for (int k = 0; k < KP; ++k) {
        float v = ls; int idx = hl;
        #pragma unroll
        for (int off = 16; off > 0; off >>= 1) {
            float ov = __shfl_xor(v, off, 32);
            int   oi = __shfl_xor(idx, off, 32);
            if (ov > v || (ov == v && oi < idx)) { v = ov; idx = oi; }
        }
        unsigned wb = __shfl(m, idx, 32);          // within-row of the pick
        ls *= ((wb >> hl) & 1u) ? 0.01f : 1.0f;
        if (hl == idx) ls = -1.0f;
        if (hl == 0) selsh[wid][half][k] = idx;
    }

    // ---- trajectory gather: issue loads NOW (overlap with MPA tail) ----
    F3 pt[3];
    #pragma unroll
    for (int i = 0; i < 3; ++i) {
        int e  = hl + 32 * i;          // 0..95
        int mm = e >> 4;               // mode 0..5
        int t  = e & 15;               // step 0..15
        int sj = selsh[wid][half][mm];
        size_t src = (((size_t)(s * NJF + sj) * NAG + a) * NSTEP + (4 + 5 * t)) * 3;
        pt[i] = *(const F3*)(trajs + src);
    }

    // ---- MPA tail: serial 6x6 on lane 0 of each 32-group ----
    if (hl == 0) {
        int   sel[KP];
        float sk[KP], sx[KP], sy[KP];
        float ssum = 0.f;
        #pragma unroll
        for (int k = 0; k < KP; ++k) {
            sel[k] = selsh[wid][half][k];
            sk[k]  = sms[wid][half][sel[k]];
            ssum  += sk[k];
            sx[k]  = exs[wid][half][sel[k]][0];
            sy[k]  = exs[wid][half][sel[k]][1];
        }
        #pragma unroll
        for (int k = 0; k < KP; ++k) sk[k] /= ssum;

        bool w2[KP][KP];
        #pragma unroll
        for (int i = 0; i < KP; ++i)
            #pragma unroll
            for (int j = 0; j < KP; ++j) {
                float dx = sx[i] - sx[j], dy = sy[i] - sy[j];
                w2[i][j] = sqrtf(dx * dx + dy * dy) < thresh;
            }

        // stable descending argsort (ties -> lower index), then MPA scan
        int order[KP]; bool used[KP] = {false,false,false,false,false,false};
        #pragma unroll
        for (int t = 0; t < KP; ++t) {
            int best = -1; float bv = 0.f;
            #pragma unroll
            for (int j = 0; j < KP; ++j)
                if (!used[j] && (best < 0 || sk[j] > bv)) { best = j; bv = sk[j]; }
            order[t] = best; used[best] = true;
        }
        #pragma unroll
        for (int t = 0; t < KP; ++t) {
            int k = order[t];
            bool any = false;
            #pragma unroll
            for (int j = 0; j < KP; ++j)
                if (w2[k][j] && sk[j] > sk[k]) any = true;
            if (any) sk[k] = 0.001f;
        }

        // normalize; softmax(log p / 0.5) == p^2 / sum(p^2)
        float s2 = 0.f;
        #pragma unroll
        for (int k = 0; k < KP; ++k) s2 += sk[k];
        #pragma unroll
        for (int k = 0; k < KP; ++k) sk[k] /= s2;
        float s3 = 0.f; float q[KP];
        #pragma unroll
        for (int k = 0; k < KP; ++k) { q[k] = sk[k] * sk[k]; s3 += q[k]; }

        const size_t SCBASE = (size_t)NSC * NAG * KP * TOUT * 3;
        size_t scb = SCBASE + ((size_t)s * NAG + a) * KP;
        #pragma unroll
        for (int k = 0; k < KP; ++k) out[scb + k] = q[k] / s3;
    }

    // ---- trajectory stores (loads were in flight during the tail) ----
    size_t ob = ((size_t)s * NAG + a) * (KP * TOUT * 3);
    #pragma unroll
    for (int i = 0; i < 3; ++i) {
        int e = hl + 32 * i;
        *(F3*)(out + ob + (size_t)e * 3) = pt[i];
    }
}

extern "C" void kernel_launch(void* const* d_in, const int* in_sizes, int n_in,
                              void* d_out, int out_size, void* d_ws, size_t ws_size,
                              hipStream_t stream) {
    const float* ag_type = (const float*)d_in[0];
    const float* trajs   = (const float*)d_in[1];
    const float* scores  = (const float*)d_in[2];
    float* out = (float*)d_out;

    womd_pp8<<<NSC * NAG / 8, 256, 0, stream>>>(ag_type, trajs, scores, out);
}